// Round 1
// baseline (161.263 us; speedup 1.0000x reference)
//
#include <hip/hip_runtime.h>
#include <stdint.h>

#define N_GAUSS 1024
#define H_DIM 768
#define W_DIM 768
#define WL_STRIDE 1040  // fp16 W row stride: row bank offset 8 -> 2-way (free)

typedef _Float16 half8  __attribute__((ext_vector_type(8)));
typedef __fp16   fp16x2 __attribute__((ext_vector_type(2)));
typedef float    f32x4  __attribute__((ext_vector_type(4)));
typedef float    v2f    __attribute__((ext_vector_type(2)));
typedef uint32_t u32x4  __attribute__((ext_vector_type(4)));

// v(y) = exp2(q(y)), q = D*y^2 + c1*y + c0 (-0.5*log2e folded in; q <= 0).
// Second-order multiplicative recurrence along the row (step Delta = 16 px):
//   v_{r+1} = v_r * rho_r,  rho_{r+1} = rho_r * sigma
//   rho_0 = exp2(Delta*(D*(2y0+Delta)+c1)),  sigma = exp2(2*D*Delta^2)
// Chains in fp32 (fp16 chains drift: absmax FAIL); fp16 only at the
// per-step cvt_pkrtz (absmax 0.5 PASS).
//
// R17: persistent-row blocks. Grid 2304 -> 768 (one block per image row,
// looping the 3 col-segments in-block). Rationale from R16 counters:
//  (a) 2304 blocks = 9/CU with 4 resident (128 regs/wave, 27 KiB LDS)
//      -> 4+4+1 residency rounds; the 1-block tail idles ~75% of the
//      machine for ~1/3 of the kernel. 768 = exactly 3/CU, all blocks
//      co-resident from t=0, uniform duration -> no tail.
//  (b) prep (1/det divide + 3 sigmoid divides/expf + LDS tables) depends
//      only on the row -> was duplicated 3x across a row's col-blocks.
//      Now once. ccf4/wl are seg-invariant; only y0/px0 change per seg.
// Epilogue reduction buffer is now DEDICATED LDS (ccf4 must survive all
// 3 segs; no aliasing). LDS 36.4 KB -> still 4 blocks/CU by LDS.
//
// Previously probed and rejected (do not retry):
//   R11 SW-pipelined LDS prefetch: +11 us (compiler already optimal)
//   R13 fp16 chains: absmax fail
//   R14 inline-asm v_pk_mul_f32: neutral (already packed)
//   R15 launch_bounds(256,6): spills acc to scratch -> 200 us. 128
//       regs/wave -> 4 waves/EU is the occupancy cap; min-bound stays 3.
//
// Geometry: block = 256 thr = 4 waves over one row; per seg, wave =
// 256-gaussian quarter (8 k-tiles) x 16 m-tiles (256 px); partials tree-
// reduced through dedicated LDS red buffer.
// MFMA 16x16x32 f16: A[m=lane&15][k=quad*8+j]; C/D col=lane&15 (ch),
// row=quad*4+reg (px). Coeff LDS: float4 {D,c1,c0,sigma} per gaussian,
// [kt][quad][slot0..8] 9-slot pad -> quad bank starts {0,4,8,12}:
// conflict-free b128. W rows {r,g,b,0} stride 1040 fp16 (2-way = free).
__global__ __launch_bounds__(256, 3) void render_kernel(
    const float2* __restrict__ means2,   // (N,2,1) -> {mx,my}
    const float4* __restrict__ covs4,    // (N,2,2) -> {a,b,c,d}
    const float4* __restrict__ colors4,  // (N,4)   -> {cr,cg,cb,alpha}
    float* __restrict__ out) {
  __shared__ __align__(16) float4 ccf4[32 * 4 * 9];     // 18,432 B coeffs
  __shared__ __align__(16) _Float16 wl[4 * WL_STRIDE];  // 8,320 B weights
  __shared__ __align__(16) float red[3 * 768];          // 9,216 B reduction

  const int t = threadIdx.x;            // 0..255
  const int h = blockIdx.x;             // image row (persistent block)
  const float scale = 1.0f / 767.0f;
  const float x = (float)h * scale;
  const float L = -0.72134752044448170368f;  // -0.5 * log2(e)
  const float Delta = 16.0f * scale;

  // ---- Row prep, ONCE per row: 4 gaussians per thread ----
#pragma unroll
  for (int i = 0; i < 4; ++i) {
    const int g = i * 256 + t;
    const float2 mn = means2[g];
    const float4 cv = covs4[g];    // a,b,c,d
    const float4 co = colors4[g];  // cr,cg,cb,alpha
    const float inv = 1.0f / (cv.x * cv.w - cv.y * cv.z);
    const float A  = L * cv.w * inv;
    const float Bc = -L * (cv.y + cv.z) * inv;
    const float D  = L * cv.x * inv;
    const float dx = x - mn.x;
    const float qa = A * dx * dx;
    const float qb = Bc * dx;
    const float c1 = fmaf(-2.0f * D, mn.y, qb);
    const float c0 = fmaf(fmaf(D, mn.y, -qb), mn.y, qa);
    const float sg = __builtin_amdgcn_exp2f(2.0f * D * Delta * Delta);
    ccf4[(g >> 5) * 36 + ((g >> 3) & 3) * 9 + (g & 7)] =
        make_float4(D, c1, c0, sg);
    const float al = co.w;
    wl[0 * WL_STRIDE + g] = (_Float16)(al / (1.0f + expf(-co.x)));
    wl[1 * WL_STRIDE + g] = (_Float16)(al / (1.0f + expf(-co.y)));
    wl[2 * WL_STRIDE + g] = (_Float16)(al / (1.0f + expf(-co.z)));
    wl[3 * WL_STRIDE + g] = (_Float16)0.0f;
  }
  __syncthreads();

  // ---- Per-wave, seg-invariant setup ----
  const int lane = t & 63;
  const int wq   = t >> 6;              // gaussian quarter 0..3
  const int m    = lane & 15;
  const int quad = lane >> 4;
  const int n4 = (m < 3) ? m : 3;

  // wave wq handles global k-tiles wq*8 .. wq*8+7
  const float4* cbase = ccf4 + (wq * 8) * 36 + quad * 9;   // + ktl*36
  const _Float16* wbase = &wl[n4 * WL_STRIDE + (wq * 8) * 32 + quad * 8];

#pragma unroll 1
  for (int seg = 0; seg < 3; ++seg) {
    const int px0  = seg * 256;
    const float y0 = (float)(px0 + m) * scale;
    const float u  = fmaf(2.0f, y0, Delta);   // rho_0 exponent helper

    f32x4 acc[16];
#pragma unroll
    for (int r = 0; r < 16; ++r) acc[r] = (f32x4){0.f, 0.f, 0.f, 0.f};

    for (int ktl = 0; ktl < 8; ++ktl) {
      const float4* cp = cbase + ktl * 36;
      float4 c[8];
#pragma unroll
      for (int j = 0; j < 8; ++j) c[j] = cp[j];   // 8x ds_read_b128, bank-clean

      const half8 b = *(const half8*)(wbase + ktl * 32);

      // anchors + ratios (2 exps per gaussian, bounded fp32)
      v2f vv[4], rr[4], ss[4];
#pragma unroll
      for (int j = 0; j < 8; ++j) {
        const float q0  = fmaf(fmaf(c[j].x, y0, c[j].y), y0, c[j].z);
        const float rex = Delta * fmaf(c[j].x, u, c[j].y);
        vv[j >> 1][j & 1] = __builtin_amdgcn_exp2f(q0);
        rr[j >> 1][j & 1] = __builtin_amdgcn_exp2f(rex);
        ss[j >> 1][j & 1] = c[j].w;
      }

#pragma unroll
      for (int r = 0; r < 16; ++r) {
        u32x4 pa;
#pragma unroll
        for (int p = 0; p < 4; ++p) {
          const fp16x2 hp = __builtin_amdgcn_cvt_pkrtz(vv[p].x, vv[p].y);
          pa[p] = __builtin_bit_cast(uint32_t, hp);
        }
        acc[r] = __builtin_amdgcn_mfma_f32_16x16x32_f16(
            __builtin_bit_cast(half8, pa), b, acc[r], 0, 0, 0);
        if (r < 15) {
#pragma unroll
          for (int p = 0; p < 4; ++p) {   // v_pk_mul_f32 chains
            vv[p] *= rr[p];
            rr[p] *= ss[p];
          }
        }
      }
    }

    // ---- Epilogue: tree-reduce the 4 gaussian-quarter partials ----
    __syncthreads();   // segs>0: wq0 done reading red from previous seg
    if (wq > 0 && m < 3) {
      float* buf = red + (wq - 1) * 768;
#pragma unroll
      for (int r = 0; r < 16; ++r) {
#pragma unroll
        for (int reg = 0; reg < 4; ++reg) {
          const int pxl = 16 * r + quad * 4 + reg;   // 0..255
          buf[pxl * 3 + m] = acc[r][reg];
        }
      }
    }
    __syncthreads();
    if (wq == 0 && m < 3) {
#pragma unroll
      for (int r = 0; r < 16; ++r) {
#pragma unroll
        for (int reg = 0; reg < 4; ++reg) {
          const int pxl = 16 * r + quad * 4 + reg;
          const float s = acc[r][reg] + red[pxl * 3 + m] +
                          red[768 + pxl * 3 + m] + red[1536 + pxl * 3 + m];
          out[((size_t)h * W_DIM + px0 + pxl) * 3 + m] = s;
        }
      }
    }
  }
}

extern "C" void kernel_launch(void* const* d_in, const int* in_sizes, int n_in,
                              void* d_out, int out_size, void* d_ws, size_t ws_size,
                              hipStream_t stream) {
  const float2* means2  = (const float2*)d_in[0];   // (N,2,1)
  const float4* covs4   = (const float4*)d_in[1];   // (N,2,2)
  const float4* colors4 = (const float4*)d_in[2];   // (N,4)
  float* out = (float*)d_out;                       // (768,768,3) fp32

  // 768 persistent blocks = one per image row, 3 col-segments in-block.
  // Exactly 3 blocks/CU resident -> no residency-tail quantization.
  render_kernel<<<dim3(H_DIM), dim3(256), 0, stream>>>(
      means2, covs4, colors4, out);
}

// Round 2
// 160.390 us; speedup vs baseline: 1.0054x; 1.0054x over previous
//
#include <hip/hip_runtime.h>
#include <stdint.h>

#define N_GAUSS 1024
#define H_DIM 768
#define W_DIM 768
#define WL_STRIDE 1040  // fp16 W row stride: row bank offset 8 -> 2-way (free)

typedef _Float16 half8  __attribute__((ext_vector_type(8)));
typedef __fp16   fp16x2 __attribute__((ext_vector_type(2)));
typedef float    f32x4  __attribute__((ext_vector_type(4)));
typedef float    v2f    __attribute__((ext_vector_type(2)));
typedef uint32_t u32x4  __attribute__((ext_vector_type(4)));

// v(y) = exp2(q(y)), q = D*y^2 + c1*y + c0 (-0.5*log2e folded in; q <= 0).
// Second-order multiplicative recurrence along the row (step Delta = 16 px):
//   v_{r+1} = v_r * rho_r,  rho_{r+1} = rho_r * sigma
//   rho_0 = exp2(Delta*(D*(2y0+Delta)+c1)),  sigma = exp2(2*D*Delta^2)
// Chains in fp32 (fp16 chains drift: absmax FAIL); fp16 only at the
// per-step cvt_pkrtz (absmax 0.5 PASS).
//
// R18: persistent-row blocks (grid 768 = 3 blocks/CU co-resident, prep
// once per row) with REGISTER-PRESSURE FIX for R17's spill regression.
// R17 evidence: WRITE_SIZE 6.9->76.8 MB, FETCH 0.25->10 MB (scratch
// traffic + L2 thrash), VGPR 64->84 (+64 AGPR = 148; peak demand had to
// exceed the (256,3) 168-reg budget somewhere -> spill). Fix here:
//  (a) c[8] coeff array (32 VGPR) ELIMINATED - each float4 cj is loaded
//      and consumed immediately in the anchor loop (peak -28 regs);
//  (b) b-operand loaded after the anchor phase, not before it;
//  (c) all addressing recomputed per seg from lane indices; nothing but
//      LDS contents + a handful of scalars live across the seg backedge.
// Inner r-loop, prep, epilogue are byte-identical to R16 (64 VGPR proven).
//
// Previously probed and rejected (do not retry):
//   R11 SW-pipelined LDS prefetch: +11 us (compiler already optimal)
//   R13 fp16 chains: absmax fail
//   R14 inline-asm v_pk_mul_f32: neutral (already packed)
//   R15 launch_bounds(256,6): forced-occupancy spill -> huge WRITE_SIZE
//   R17 seg loop w/ c[8] array live: spill -> 76.8 MB writes, 121 us
//
// Geometry: block = 256 thr = 4 waves over one row; per seg, wave =
// 256-gaussian quarter (8 k-tiles) x 16 m-tiles (256 px); partials tree-
// reduced through dedicated LDS red buffer (ccf4 must outlive all segs).
// MFMA 16x16x32 f16: A[m=lane&15][k=quad*8+j]; C/D col=lane&15 (ch),
// row=quad*4+reg (px). Coeff LDS: float4 {D,c1,c0,sigma} per gaussian,
// [kt][quad][slot0..8] 9-slot pad -> quad bank starts {0,4,8,12}:
// conflict-free b128. W rows {r,g,b,0} stride 1040 fp16 (2-way = free).
__global__ __launch_bounds__(256, 3) void render_kernel(
    const float2* __restrict__ means2,   // (N,2,1) -> {mx,my}
    const float4* __restrict__ covs4,    // (N,2,2) -> {a,b,c,d}
    const float4* __restrict__ colors4,  // (N,4)   -> {cr,cg,cb,alpha}
    float* __restrict__ out) {
  __shared__ __align__(16) float4 ccf4[32 * 4 * 9];     // 18,432 B coeffs
  __shared__ __align__(16) _Float16 wl[4 * WL_STRIDE];  // 8,320 B weights
  __shared__ __align__(16) float red[3 * 768];          // 9,216 B reduction

  const int t = threadIdx.x;            // 0..255
  const int h = blockIdx.x;             // image row (persistent block)
  const float scale = 1.0f / 767.0f;
  const float x = (float)h * scale;
  const float L = -0.72134752044448170368f;  // -0.5 * log2(e)
  const float Delta = 16.0f * scale;

  // ---- Row prep, ONCE per row: 4 gaussians per thread ----
#pragma unroll
  for (int i = 0; i < 4; ++i) {
    const int g = i * 256 + t;
    const float2 mn = means2[g];
    const float4 cv = covs4[g];    // a,b,c,d
    const float4 co = colors4[g];  // cr,cg,cb,alpha
    const float inv = 1.0f / (cv.x * cv.w - cv.y * cv.z);
    const float A  = L * cv.w * inv;
    const float Bc = -L * (cv.y + cv.z) * inv;
    const float D  = L * cv.x * inv;
    const float dx = x - mn.x;
    const float qa = A * dx * dx;
    const float qb = Bc * dx;
    const float c1 = fmaf(-2.0f * D, mn.y, qb);
    const float c0 = fmaf(fmaf(D, mn.y, -qb), mn.y, qa);
    const float sg = __builtin_amdgcn_exp2f(2.0f * D * Delta * Delta);
    ccf4[(g >> 5) * 36 + ((g >> 3) & 3) * 9 + (g & 7)] =
        make_float4(D, c1, c0, sg);
    const float al = co.w;
    wl[0 * WL_STRIDE + g] = (_Float16)(al / (1.0f + expf(-co.x)));
    wl[1 * WL_STRIDE + g] = (_Float16)(al / (1.0f + expf(-co.y)));
    wl[2 * WL_STRIDE + g] = (_Float16)(al / (1.0f + expf(-co.z)));
    wl[3 * WL_STRIDE + g] = (_Float16)0.0f;
  }
  __syncthreads();

  // ---- Lane decomposition (cheap scalars, live across segs) ----
  const int lane = t & 63;
  const int wq   = t >> 6;              // gaussian quarter 0..3
  const int m    = lane & 15;
  const int quad = lane >> 4;
  const int n4 = (m < 3) ? m : 3;

#pragma unroll 1
  for (int seg = 0; seg < 3; ++seg) {
    const int px0  = seg * 256;
    const float y0 = (float)(px0 + m) * scale;
    const float u  = fmaf(2.0f, y0, Delta);   // rho_0 exponent helper

    f32x4 acc[16];
#pragma unroll
    for (int r = 0; r < 16; ++r) acc[r] = (f32x4){0.f, 0.f, 0.f, 0.f};

    for (int ktl = 0; ktl < 8; ++ktl) {
      // anchors + ratios (2 exps per gaussian, bounded fp32).
      // Coeff float4 loaded and CONSUMED per j - no c[8] array (R17 fix).
      const float4* cp = ccf4 + (wq * 8 + ktl) * 36 + quad * 9;
      v2f vv[4], rr[4], ss[4];
#pragma unroll
      for (int j = 0; j < 8; ++j) {
        const float4 cj = cp[j];                    // ds_read_b128
        const float q0  = fmaf(fmaf(cj.x, y0, cj.y), y0, cj.z);
        const float rex = Delta * fmaf(cj.x, u, cj.y);
        vv[j >> 1][j & 1] = __builtin_amdgcn_exp2f(q0);
        rr[j >> 1][j & 1] = __builtin_amdgcn_exp2f(rex);
        ss[j >> 1][j & 1] = cj.w;
      }

      const half8 b =
          *(const half8*)(&wl[n4 * WL_STRIDE + (wq * 8 + ktl) * 32 + quad * 8]);

#pragma unroll
      for (int r = 0; r < 16; ++r) {
        u32x4 pa;
#pragma unroll
        for (int p = 0; p < 4; ++p) {
          const fp16x2 hp = __builtin_amdgcn_cvt_pkrtz(vv[p].x, vv[p].y);
          pa[p] = __builtin_bit_cast(uint32_t, hp);
        }
        acc[r] = __builtin_amdgcn_mfma_f32_16x16x32_f16(
            __builtin_bit_cast(half8, pa), b, acc[r], 0, 0, 0);
        if (r < 15) {
#pragma unroll
          for (int p = 0; p < 4; ++p) {   // v_pk_mul_f32 chains
            vv[p] *= rr[p];
            rr[p] *= ss[p];
          }
        }
      }
    }

    // ---- Epilogue: tree-reduce the 4 gaussian-quarter partials ----
    __syncthreads();   // segs>0: wq0 done reading red from previous seg
    if (wq > 0 && m < 3) {
      float* buf = red + (wq - 1) * 768;
#pragma unroll
      for (int r = 0; r < 16; ++r) {
#pragma unroll
        for (int reg = 0; reg < 4; ++reg) {
          const int pxl = 16 * r + quad * 4 + reg;   // 0..255
          buf[pxl * 3 + m] = acc[r][reg];
        }
      }
    }
    __syncthreads();
    if (wq == 0 && m < 3) {
#pragma unroll
      for (int r = 0; r < 16; ++r) {
#pragma unroll
        for (int reg = 0; reg < 4; ++reg) {
          const int pxl = 16 * r + quad * 4 + reg;
          const float s = acc[r][reg] + red[pxl * 3 + m] +
                          red[768 + pxl * 3 + m] + red[1536 + pxl * 3 + m];
          out[((size_t)h * W_DIM + px0 + pxl) * 3 + m] = s;
        }
      }
    }
  }
}

extern "C" void kernel_launch(void* const* d_in, const int* in_sizes, int n_in,
                              void* d_out, int out_size, void* d_ws, size_t ws_size,
                              hipStream_t stream) {
  const float2* means2  = (const float2*)d_in[0];   // (N,2,1)
  const float4* covs4   = (const float4*)d_in[1];   // (N,2,2)
  const float4* colors4 = (const float4*)d_in[2];   // (N,4)
  float* out = (float*)d_out;                       // (768,768,3) fp32

  // 768 persistent blocks = one per image row, 3 col-segments in-block.
  // Exactly 3 blocks/CU resident -> no residency-tail quantization.
  render_kernel<<<dim3(H_DIM), dim3(256), 0, stream>>>(
      means2, covs4, colors4, out);
}

// Round 3
// 111.817 us; speedup vs baseline: 1.4422x; 1.4344x over previous
//
#include <hip/hip_runtime.h>
#include <stdint.h>

#define N_GAUSS 1024
#define H_DIM 768
#define W_DIM 768
#define WL_STRIDE 1040  // fp16 W row stride: row bank offset 8 -> 2-way (free)

typedef _Float16 half8  __attribute__((ext_vector_type(8)));
typedef __fp16   fp16x2 __attribute__((ext_vector_type(2)));
typedef float    f32x4  __attribute__((ext_vector_type(4)));
typedef float    v2f    __attribute__((ext_vector_type(2)));
typedef uint32_t u32x4  __attribute__((ext_vector_type(4)));

// v(y) = exp2(q(y)), q = D*y^2 + c1*y + c0 (-0.5*log2e folded in; q <= 0).
// Second-order multiplicative recurrence along the row (step Delta = 16 px):
//   v_{r+1} = v_r * rho_r,  rho_{r+1} = rho_r * sigma
//   rho_0 = exp2(Delta*(D*(2y0+Delta)+c1)),  sigma = exp2(2*D*Delta^2)
// Chains in fp32 (fp16 chains drift: absmax FAIL); fp16 only at the
// per-step cvt_pkrtz (absmax 0.5 PASS).
//
// R19: R16 structure restored (one block = one col-segment, NO in-block
// seg loop) with the segment width retiled 256 -> 192 px:
//   grid 2304 (9 blocks/CU) -> 3072 (12 blocks/CU).
// Rationale: R16 runs 64 VGPR + 64 AGPR = exactly 128 regs/wave ->
// 16 waves/CU -> 4 blocks resident (registers, not LDS, are the cap).
// 9 blocks/CU executes as rounds 4+4+1: the 1-block tail idles 75% of
// the machine for ~1/3 of the kernel (matches measured VALUBusy 66%,
// Occupancy 30%). 12 blocks/CU packs perfectly for residency 4 (4+4+4),
// 6 (6+6), or 3 (4x3). Cost: chain amortization 1/12 vs 1/16 (+1.4%
// VALU) + one extra prep per row (+~2%). acc 16->12 (48 AGPR).
//
// Probed and rejected (do not retry):
//   R11 SW-pipelined LDS prefetch: +11 us (compiler already optimal)
//   R13 fp16 chains: absmax fail
//   R14 inline-asm v_pk_mul_f32: neutral (already packed)
//   R15 launch_bounds(256,6): forced-occupancy spill -> 200 us
//   R17/R18 persistent-row blocks w/ in-block seg loop: compiler emits
//       ~70 MB/dispatch of write-mostly scratch (WRITE 6.9->76.8 MB,
//       VGPR 84) in BOTH variants incl. zero-live-array version; 112 us.
//       Root cause never isolated -- do not reintroduce the seg loop.
//
// Geometry: block = 256 thr = 4 waves over one 192-px col-group; wave =
// 256-gaussian quarter (8 k-tiles) x 12 m-tiles (192 px); partials tree-
// reduced through LDS (aliased over the dead coeff table). 3072 blocks.
// MFMA 16x16x32 f16: A[m=lane&15][k=quad*8+j]; C/D col=lane&15 (ch),
// row=quad*4+reg (px). Coeff LDS: float4 {D,c1,c0,sigma} per gaussian,
// [kt][quad][slot0..8] 9-slot pad -> quad bank starts {0,4,8,12}:
// conflict-free b128. W rows {r,g,b,0} stride 1040 fp16 (2-way = free).
__global__ __launch_bounds__(256, 3) void render_kernel(
    const float2* __restrict__ means2,   // (N,2,1) -> {mx,my}
    const float4* __restrict__ covs4,    // (N,2,2) -> {a,b,c,d}
    const float4* __restrict__ colors4,  // (N,4)   -> {cr,cg,cb,alpha}
    float* __restrict__ out) {
  __shared__ __align__(16) float4 ccf4[32 * 4 * 9];     // 18,432 B (+ red buf)
  __shared__ __align__(16) _Float16 wl[4 * WL_STRIDE];  // 8,320 B

  const int t   = threadIdx.x;          // 0..255
  const int h   = blockIdx.x >> 2;      // image row
  const int seg = blockIdx.x & 3;       // 192-px col-group
  const float scale = 1.0f / 767.0f;
  const float x = (float)h * scale;
  const float L = -0.72134752044448170368f;  // -0.5 * log2(e)
  const float Delta = 16.0f * scale;

  // ---- Block prep: 4 gaussians per thread ----
#pragma unroll
  for (int i = 0; i < 4; ++i) {
    const int g = i * 256 + t;
    const float2 mn = means2[g];
    const float4 cv = covs4[g];    // a,b,c,d
    const float4 co = colors4[g];  // cr,cg,cb,alpha
    const float inv = 1.0f / (cv.x * cv.w - cv.y * cv.z);
    const float A  = L * cv.w * inv;
    const float Bc = -L * (cv.y + cv.z) * inv;
    const float D  = L * cv.x * inv;
    const float dx = x - mn.x;
    const float qa = A * dx * dx;
    const float qb = Bc * dx;
    const float c1 = fmaf(-2.0f * D, mn.y, qb);
    const float c0 = fmaf(fmaf(D, mn.y, -qb), mn.y, qa);
    const float sg = __builtin_amdgcn_exp2f(2.0f * D * Delta * Delta);
    ccf4[(g >> 5) * 36 + ((g >> 3) & 3) * 9 + (g & 7)] =
        make_float4(D, c1, c0, sg);
    const float al = co.w;
    wl[0 * WL_STRIDE + g] = (_Float16)(al / (1.0f + expf(-co.x)));
    wl[1 * WL_STRIDE + g] = (_Float16)(al / (1.0f + expf(-co.y)));
    wl[2 * WL_STRIDE + g] = (_Float16)(al / (1.0f + expf(-co.z)));
    wl[3 * WL_STRIDE + g] = (_Float16)0.0f;
  }
  __syncthreads();

  // ---- Per-wave setup: wave = gaussian quarter, 12 m-tiles (192 px) ----
  const int lane = t & 63;
  const int wq   = t >> 6;              // gaussian quarter 0..3
  const int m    = lane & 15;
  const int quad = lane >> 4;
  const int px0  = seg * 192;
  const float y0 = (float)(px0 + m) * scale;
  const float u  = fmaf(2.0f, y0, Delta);   // rho_0 exponent helper
  const int n4 = (m < 3) ? m : 3;

  // wave wq handles global k-tiles wq*8 .. wq*8+7
  const float4* cbase = ccf4 + (wq * 8) * 36 + quad * 9;   // + ktl*36
  const _Float16* wbase = &wl[n4 * WL_STRIDE + (wq * 8) * 32 + quad * 8];

  f32x4 acc[12];
#pragma unroll
  for (int r = 0; r < 12; ++r) acc[r] = (f32x4){0.f, 0.f, 0.f, 0.f};

  for (int ktl = 0; ktl < 8; ++ktl) {
    const float4* cp = cbase + ktl * 36;
    float4 c[8];
#pragma unroll
    for (int j = 0; j < 8; ++j) c[j] = cp[j];   // 8x ds_read_b128, bank-clean

    const half8 b = *(const half8*)(wbase + ktl * 32);

    // anchors + ratios (2 exps per gaussian, bounded fp32)
    v2f vv[4], rr[4], ss[4];
#pragma unroll
    for (int j = 0; j < 8; ++j) {
      const float q0  = fmaf(fmaf(c[j].x, y0, c[j].y), y0, c[j].z);
      const float rex = Delta * fmaf(c[j].x, u, c[j].y);
      vv[j >> 1][j & 1] = __builtin_amdgcn_exp2f(q0);
      rr[j >> 1][j & 1] = __builtin_amdgcn_exp2f(rex);
      ss[j >> 1][j & 1] = c[j].w;
    }

#pragma unroll
    for (int r = 0; r < 12; ++r) {
      u32x4 pa;
#pragma unroll
      for (int p = 0; p < 4; ++p) {
        const fp16x2 hp = __builtin_amdgcn_cvt_pkrtz(vv[p].x, vv[p].y);
        pa[p] = __builtin_bit_cast(uint32_t, hp);
      }
      acc[r] = __builtin_amdgcn_mfma_f32_16x16x32_f16(
          __builtin_bit_cast(half8, pa), b, acc[r], 0, 0, 0);
      if (r < 11) {
#pragma unroll
        for (int p = 0; p < 4; ++p) {   // v_pk_mul_f32 chains
          vv[p] *= rr[p];
          rr[p] *= ss[p];
        }
      }
    }
  }

  // ---- Epilogue: tree-reduce the 4 gaussian-quarter partials via LDS ----
  __syncthreads();                       // all waves done reading ccf4/wl
  float* red = (float*)ccf4;             // 3 x 576 floats, aliased
  if (wq > 0 && m < 3) {
    float* buf = red + (wq - 1) * 576;
#pragma unroll
    for (int r = 0; r < 12; ++r) {
#pragma unroll
      for (int reg = 0; reg < 4; ++reg) {
        const int pxl = 16 * r + quad * 4 + reg;   // 0..191
        buf[pxl * 3 + m] = acc[r][reg];
      }
    }
  }
  __syncthreads();
  if (wq == 0 && m < 3) {
#pragma unroll
    for (int r = 0; r < 12; ++r) {
#pragma unroll
      for (int reg = 0; reg < 4; ++reg) {
        const int pxl = 16 * r + quad * 4 + reg;
        const float s = acc[r][reg] + red[pxl * 3 + m] +
                        red[576 + pxl * 3 + m] + red[1152 + pxl * 3 + m];
        out[((size_t)h * W_DIM + px0 + pxl) * 3 + m] = s;
      }
    }
  }
}

extern "C" void kernel_launch(void* const* d_in, const int* in_sizes, int n_in,
                              void* d_out, int out_size, void* d_ws, size_t ws_size,
                              hipStream_t stream) {
  const float2* means2  = (const float2*)d_in[0];   // (N,2,1)
  const float4* covs4   = (const float4*)d_in[1];   // (N,2,2)
  const float4* colors4 = (const float4*)d_in[2];   // (N,4)
  float* out = (float*)d_out;                       // (768,768,3) fp32

  // 3072 blocks = 768 rows x 4 col-groups (192 px) = 12 blocks/CU:
  // divisible by residency 4 or 6 -> even execution rounds, no tail.
  render_kernel<<<dim3(H_DIM * 4), dim3(256), 0, stream>>>(
      means2, covs4, colors4, out);
}

// Round 4
// 104.436 us; speedup vs baseline: 1.5441x; 1.0707x over previous
//
#include <hip/hip_runtime.h>
#include <stdint.h>

#define N_GAUSS 1024
#define H_DIM 768
#define W_DIM 768
#define WL_STRIDE 1040  // fp16 W row stride: row bank offset 8 -> 2-way (free)

typedef _Float16 half8  __attribute__((ext_vector_type(8)));
typedef __fp16   fp16x2 __attribute__((ext_vector_type(2)));
typedef float    f32x4  __attribute__((ext_vector_type(4)));
typedef float    v2f    __attribute__((ext_vector_type(2)));
typedef uint32_t u32x4  __attribute__((ext_vector_type(4)));

// v(y) = exp2(q(y)), q = D*y^2 + c1*y + c0 (-0.5*log2e folded in; q <= 0).
// Second-order multiplicative recurrence along the row (step Delta = 16 px):
//   v_{r+1} = v_r * rho_r,  rho_{r+1} = rho_r * sigma
//   rho_0 = exp2(Delta*(D*(2y0+Delta)+c1)),  sigma = exp2(2*D*Delta^2)
// Chains in fp32 (fp16 chains drift: absmax FAIL); fp16 only at the
// per-step cvt_pkrtz (absmax 0.5 PASS -- dominated by fp16 A quantization,
// not chain length: absmax identical at r=12 and r=16).
//
// R20: R16 main loop VERBATIM (proven best: 64.5 us dispatch) + parallel
// coalesced epilogue. R16's epilogue was serial: waves 1-3 write partials
// (12/64 lanes), then wave 0 ALONE sums and issues 144 strided scalar
// stores while 3 waves idle. Now: all 4 waves write partial sets to LDS
// (4 x 768 f32 over the dead coeff table), then all 4 waves sum disjoint
// 192-float slices with ALL 64 lanes and store the block's contiguous
// 768-float output span fully coalesced (3 store rounds/wave).
//
// Tiling trade-off curve measured across R16(r=16,2304blk)/R19(r=12,
// 3072blk): per-px issue (anchor/r + chain) vs waves/SIMD (floor(512/
// (56+4r))) is FLAT -- anchor duplication cancels occupancy gains at
// every r. Segment/wave re-tiling is a dead end; r=16 geometry optimal.
//
// Probed and rejected (do not retry):
//   R11 SW-pipelined LDS prefetch: +11 us (compiler already optimal)
//   R13 fp16 chains: absmax fail
//   R14 inline-asm v_pk_mul_f32: neutral (already packed)
//   R15 launch_bounds(256,6) w/ acc[16]: forced spill -> 200 us
//   R17/R18 persistent-row seg loop: ~70 MB scratch daemon, 112-121 us
//   R19 192-px retile (12 blocks/CU even rounds): 69.5 us -- occupancy
//       packing theory dead; VALUBusy stuck ~68% regardless of rounds
//
// Geometry: block = 256 thr = 4 waves over one 256-px col-group; wave =
// 256-gaussian quarter (8 k-tiles) x 16 m-tiles (256 px). 2304 blocks.
// MFMA 16x16x32 f16: A[m=lane&15][k=quad*8+j]; C/D col=lane&15 (ch),
// row=quad*4+reg (px). Coeff LDS: float4 {D,c1,c0,sigma} per gaussian,
// [kt][quad][slot0..8] 9-slot pad -> quad bank starts {0,4,8,12}:
// conflict-free b128. W rows {r,g,b,0} stride 1040 fp16 (2-way = free).
__global__ __launch_bounds__(256, 3) void render_kernel(
    const float2* __restrict__ means2,   // (N,2,1) -> {mx,my}
    const float4* __restrict__ covs4,    // (N,2,2) -> {a,b,c,d}
    const float4* __restrict__ colors4,  // (N,4)   -> {cr,cg,cb,alpha}
    float* __restrict__ out) {
  __shared__ __align__(16) float4 ccf4[32 * 4 * 9];     // 18,432 B (+ red buf)
  __shared__ __align__(16) _Float16 wl[4 * WL_STRIDE];  // 8,320 B

  const int t   = threadIdx.x;          // 0..255
  const int h   = blockIdx.x / 3;       // image row
  const int seg = blockIdx.x % 3;       // 256-px col-group
  const float scale = 1.0f / 767.0f;
  const float x = (float)h * scale;
  const float L = -0.72134752044448170368f;  // -0.5 * log2(e)
  const float Delta = 16.0f * scale;

  // ---- Block prep: 4 gaussians per thread ----
#pragma unroll
  for (int i = 0; i < 4; ++i) {
    const int g = i * 256 + t;
    const float2 mn = means2[g];
    const float4 cv = covs4[g];    // a,b,c,d
    const float4 co = colors4[g];  // cr,cg,cb,alpha
    const float inv = 1.0f / (cv.x * cv.w - cv.y * cv.z);
    const float A  = L * cv.w * inv;
    const float Bc = -L * (cv.y + cv.z) * inv;
    const float D  = L * cv.x * inv;
    const float dx = x - mn.x;
    const float qa = A * dx * dx;
    const float qb = Bc * dx;
    const float c1 = fmaf(-2.0f * D, mn.y, qb);
    const float c0 = fmaf(fmaf(D, mn.y, -qb), mn.y, qa);
    const float sg = __builtin_amdgcn_exp2f(2.0f * D * Delta * Delta);
    ccf4[(g >> 5) * 36 + ((g >> 3) & 3) * 9 + (g & 7)] =
        make_float4(D, c1, c0, sg);
    const float al = co.w;
    wl[0 * WL_STRIDE + g] = (_Float16)(al / (1.0f + expf(-co.x)));
    wl[1 * WL_STRIDE + g] = (_Float16)(al / (1.0f + expf(-co.y)));
    wl[2 * WL_STRIDE + g] = (_Float16)(al / (1.0f + expf(-co.z)));
    wl[3 * WL_STRIDE + g] = (_Float16)0.0f;
  }
  __syncthreads();

  // ---- Per-wave setup: wave = gaussian quarter, 16 m-tiles (256 px) ----
  const int lane = t & 63;
  const int wq   = t >> 6;              // gaussian quarter 0..3
  const int m    = lane & 15;
  const int quad = lane >> 4;
  const int px0  = seg * 256;
  const float y0 = (float)(px0 + m) * scale;
  const float u  = fmaf(2.0f, y0, Delta);   // rho_0 exponent helper
  const int n4 = (m < 3) ? m : 3;

  // wave wq handles global k-tiles wq*8 .. wq*8+7
  const float4* cbase = ccf4 + (wq * 8) * 36 + quad * 9;   // + ktl*36
  const _Float16* wbase = &wl[n4 * WL_STRIDE + (wq * 8) * 32 + quad * 8];

  f32x4 acc[16];
#pragma unroll
  for (int r = 0; r < 16; ++r) acc[r] = (f32x4){0.f, 0.f, 0.f, 0.f};

  for (int ktl = 0; ktl < 8; ++ktl) {
    const float4* cp = cbase + ktl * 36;
    float4 c[8];
#pragma unroll
    for (int j = 0; j < 8; ++j) c[j] = cp[j];   // 8x ds_read_b128, bank-clean

    const half8 b = *(const half8*)(wbase + ktl * 32);

    // anchors + ratios (2 exps per gaussian, bounded fp32)
    v2f vv[4], rr[4], ss[4];
#pragma unroll
    for (int j = 0; j < 8; ++j) {
      const float q0  = fmaf(fmaf(c[j].x, y0, c[j].y), y0, c[j].z);
      const float rex = Delta * fmaf(c[j].x, u, c[j].y);
      vv[j >> 1][j & 1] = __builtin_amdgcn_exp2f(q0);
      rr[j >> 1][j & 1] = __builtin_amdgcn_exp2f(rex);
      ss[j >> 1][j & 1] = c[j].w;
    }

#pragma unroll
    for (int r = 0; r < 16; ++r) {
      u32x4 pa;
#pragma unroll
      for (int p = 0; p < 4; ++p) {
        const fp16x2 hp = __builtin_amdgcn_cvt_pkrtz(vv[p].x, vv[p].y);
        pa[p] = __builtin_bit_cast(uint32_t, hp);
      }
      acc[r] = __builtin_amdgcn_mfma_f32_16x16x32_f16(
          __builtin_bit_cast(half8, pa), b, acc[r], 0, 0, 0);
      if (r < 15) {
#pragma unroll
        for (int p = 0; p < 4; ++p) {   // v_pk_mul_f32 chains
          vv[p] *= rr[p];
          rr[p] *= ss[p];
        }
      }
    }
  }

  // ---- Epilogue: ALL 4 waves write partials, ALL 4 waves sum+store ----
  __syncthreads();                       // all waves done reading ccf4/wl
  float* red = (float*)ccf4;             // 4 sets x 768 floats = 12,288 B
  if (m < 3) {
    float* buf = red + wq * 768;
#pragma unroll
    for (int r = 0; r < 16; ++r) {
#pragma unroll
      for (int reg = 0; reg < 4; ++reg) {
        const int pxl = 16 * r + quad * 4 + reg;   // 0..255
        buf[pxl * 3 + m] = acc[r][reg];            // banks distinct mod 32
      }
    }
  }
  __syncthreads();
  // Block output span is contiguous: out[(h*768+px0)*3 .. +768). Each wave
  // sums a disjoint 192-float slice across the 4 sets, 64 lanes coalesced.
  {
    float* obase = out + ((size_t)h * W_DIM + px0) * 3;
    const int base = wq * 192;
#pragma unroll
    for (int i = 0; i < 3; ++i) {
      const int f = base + i * 64 + lane;
      const float s = red[f] + red[768 + f] + red[1536 + f] + red[2304 + f];
      obase[f] = s;
    }
  }
}

extern "C" void kernel_launch(void* const* d_in, const int* in_sizes, int n_in,
                              void* d_out, int out_size, void* d_ws, size_t ws_size,
                              hipStream_t stream) {
  const float2* means2  = (const float2*)d_in[0];   // (N,2,1)
  const float4* covs4   = (const float4*)d_in[1];   // (N,2,2)
  const float4* colors4 = (const float4*)d_in[2];   // (N,4)
  float* out = (float*)d_out;                       // (768,768,3) fp32

  // 2304 blocks = 768 rows x 3 col-groups; 256 thr = 4 gaussian-quarter waves.
  render_kernel<<<dim3(H_DIM * 3), dim3(256), 0, stream>>>(
      means2, covs4, colors4, out);
}

// Round 5
// 103.079 us; speedup vs baseline: 1.5645x; 1.0132x over previous
//
#include <hip/hip_runtime.h>
#include <stdint.h>

#define N_GAUSS 1024
#define H_DIM 768
#define W_DIM 768
#define WL_STRIDE 1040  // fp16 W row stride: row bank offset 8 -> 2-way (free)

typedef _Float16 half8  __attribute__((ext_vector_type(8)));
typedef __fp16   fp16x2 __attribute__((ext_vector_type(2)));
typedef float    f32x4  __attribute__((ext_vector_type(4)));
typedef float    v2f    __attribute__((ext_vector_type(2)));
typedef uint32_t u32x4  __attribute__((ext_vector_type(4)));

// v(y) = exp2(q(y)), q = D*y^2 + c1*y + c0 (-0.5*log2e folded in; q <= 0).
// Second-order multiplicative recurrence along the row (step Delta = 16 px):
//   v_{r+1} = v_r * rho_r,  rho_{r+1} = rho_r * sigma
//   rho_0 = exp2(Delta*(D*(2y0+Delta)+c1)),  sigma = exp2(2*D*Delta^2)
// Chains in fp32 (fp16 chains drift: absmax FAIL); fp16 only at the
// per-step cvt_pkrtz (absmax 0.5 PASS; 12-step chains validated in R19).
//
// R21: single-round geometry. One block per image ROW (768 blocks), one
// wave per 192-px column segment; each wave loops ALL 32 k-tiles (1024
// gaussians) -> owns its output tile outright, NO cross-wave reduction.
//  - 768 blocks = exactly 3 blocks/CU = 3 waves/SIMD: every block
//    resident from t=0, one uniform round -> the 4+4+1 residency tail
//    (R16/R20: last round ran 1 wave/SIMD for ~1/3 of the kernel) is
//    structurally impossible.
//  - prep (divides/sigmoids/LDS tables) now once per row, was 3x.
//  - NO in-block multi-segment loop: each wave has a FIXED y0/seg, so
//    the R17/R18 loop-carried structure that triggered the ~70 MB
//    scratch daemon never appears; k-loop just runs 32 iters of the
//    same body that ran 8.
//  - costs: anchors x1.33 (192 vs 256-px amortization), occupancy 3
//    waves/SIMD (vs 4). acc 16->12 (48 AGPR).
//  - epilogue: wave-private LDS transpose (no cross-wave barrier need;
//    one safety __syncthreads) + 9 fully-coalesced 256B stores/wave.
//
// Probed and rejected (do not retry):
//   R11 SW-pipelined LDS prefetch: +11 us (compiler already optimal)
//   R13 fp16 chains (16-step): absmax 3.0 FAIL
//   R14 inline-asm v_pk_mul_f32: neutral (already packed)
//   R15 launch_bounds(256,6) w/ acc[16]: forced spill -> 200 us
//   R17/R18 persistent-row seg loop: ~70 MB scratch daemon, 112-121 us
//   R19 192-px retile at 3072 blocks: anchor duplication ate the
//       packing win (69.5 us) -- but 12-step chains passed absmax 0.5
//   R20 parallel epilogue: WIN 64.5 -> 58.2 us (current anchor)
//
// MFMA 16x16x32 f16: A[m=lane&15][k=quad*8+j]; C/D col=lane&15 (ch),
// row=quad*4+reg (px). Coeff LDS: float4 {D,c1,c0,sigma} per gaussian,
// [kt][quad][slot0..8] 9-slot pad -> quad bank starts {0,4,8,12}:
// conflict-free b128. W rows {r,g,b,0} stride 1040 fp16 (2-way = free).
__global__ __launch_bounds__(256, 3) void render_kernel(
    const float2* __restrict__ means2,   // (N,2,1) -> {mx,my}
    const float4* __restrict__ covs4,    // (N,2,2) -> {a,b,c,d}
    const float4* __restrict__ colors4,  // (N,4)   -> {cr,cg,cb,alpha}
    float* __restrict__ out) {
  __shared__ __align__(16) float4 ccf4[32 * 4 * 9];     // 18,432 B coeffs
  __shared__ __align__(16) _Float16 wl[4 * WL_STRIDE];  // 8,320 B weights
  __shared__ __align__(16) float red[4 * 576];          // 9,216 B transpose

  const int t = threadIdx.x;            // 0..255
  const int h = blockIdx.x;             // image row
  const float scale = 1.0f / 767.0f;
  const float x = (float)h * scale;
  const float L = -0.72134752044448170368f;  // -0.5 * log2(e)
  const float Delta = 16.0f * scale;

  // ---- Row prep, once per row: 4 gaussians per thread ----
#pragma unroll
  for (int i = 0; i < 4; ++i) {
    const int g = i * 256 + t;
    const float2 mn = means2[g];
    const float4 cv = covs4[g];    // a,b,c,d
    const float4 co = colors4[g];  // cr,cg,cb,alpha
    const float inv = 1.0f / (cv.x * cv.w - cv.y * cv.z);
    const float A  = L * cv.w * inv;
    const float Bc = -L * (cv.y + cv.z) * inv;
    const float D  = L * cv.x * inv;
    const float dx = x - mn.x;
    const float qa = A * dx * dx;
    const float qb = Bc * dx;
    const float c1 = fmaf(-2.0f * D, mn.y, qb);
    const float c0 = fmaf(fmaf(D, mn.y, -qb), mn.y, qa);
    const float sg = __builtin_amdgcn_exp2f(2.0f * D * Delta * Delta);
    ccf4[(g >> 5) * 36 + ((g >> 3) & 3) * 9 + (g & 7)] =
        make_float4(D, c1, c0, sg);
    const float al = co.w;
    wl[0 * WL_STRIDE + g] = (_Float16)(al / (1.0f + expf(-co.x)));
    wl[1 * WL_STRIDE + g] = (_Float16)(al / (1.0f + expf(-co.y)));
    wl[2 * WL_STRIDE + g] = (_Float16)(al / (1.0f + expf(-co.z)));
    wl[3 * WL_STRIDE + g] = (_Float16)0.0f;
  }
  __syncthreads();

  // ---- Per-wave setup: wave = one 192-px col-seg, ALL 1024 gaussians ----
  const int lane = t & 63;
  const int wq   = t >> 6;              // column segment 0..3
  const int m    = lane & 15;
  const int quad = lane >> 4;
  const int px0  = wq * 192;
  const float y0 = (float)(px0 + m) * scale;
  const float u  = fmaf(2.0f, y0, Delta);   // rho_0 exponent helper
  const int n4 = (m < 3) ? m : 3;

  const float4* cbase = ccf4 + quad * 9;               // + ktl*36
  const _Float16* wbase = &wl[n4 * WL_STRIDE + quad * 8];  // + ktl*32

  f32x4 acc[12];
#pragma unroll
  for (int r = 0; r < 12; ++r) acc[r] = (f32x4){0.f, 0.f, 0.f, 0.f};

  for (int ktl = 0; ktl < 32; ++ktl) {
    const float4* cp = cbase + ktl * 36;
    float4 c[8];
#pragma unroll
    for (int j = 0; j < 8; ++j) c[j] = cp[j];   // 8x ds_read_b128, bank-clean

    const half8 b = *(const half8*)(wbase + ktl * 32);

    // anchors + ratios (2 exps per gaussian, bounded fp32)
    v2f vv[4], rr[4], ss[4];
#pragma unroll
    for (int j = 0; j < 8; ++j) {
      const float q0  = fmaf(fmaf(c[j].x, y0, c[j].y), y0, c[j].z);
      const float rex = Delta * fmaf(c[j].x, u, c[j].y);
      vv[j >> 1][j & 1] = __builtin_amdgcn_exp2f(q0);
      rr[j >> 1][j & 1] = __builtin_amdgcn_exp2f(rex);
      ss[j >> 1][j & 1] = c[j].w;
    }

#pragma unroll
    for (int r = 0; r < 12; ++r) {
      u32x4 pa;
#pragma unroll
      for (int p = 0; p < 4; ++p) {
        const fp16x2 hp = __builtin_amdgcn_cvt_pkrtz(vv[p].x, vv[p].y);
        pa[p] = __builtin_bit_cast(uint32_t, hp);
      }
      acc[r] = __builtin_amdgcn_mfma_f32_16x16x32_f16(
          __builtin_bit_cast(half8, pa), b, acc[r], 0, 0, 0);
      if (r < 11) {
#pragma unroll
        for (int p = 0; p < 4; ++p) {   // v_pk_mul_f32 chains
          vv[p] *= rr[p];
          rr[p] *= ss[p];
        }
      }
    }
  }

  // ---- Epilogue: wave-private LDS transpose + coalesced store ----
  // Wave owns its (row, seg) tile outright; no cross-wave reduction.
  __syncthreads();                      // all waves done reading ccf4/wl
  float* buf = red + wq * 576;
  if (m < 3) {
#pragma unroll
    for (int r = 0; r < 12; ++r) {
#pragma unroll
      for (int reg = 0; reg < 4; ++reg) {
        const int pxl = 16 * r + quad * 4 + reg;   // 0..191
        buf[pxl * 3 + m] = acc[r][reg];            // banks distinct mod 32
      }
    }
  }
  __syncthreads();                      // safety: order write->read
  {
    float* obase = out + ((size_t)h * W_DIM + px0) * 3;
#pragma unroll
    for (int i = 0; i < 9; ++i) {       // 576 floats, 64 lanes: 9 rounds
      const int f = i * 64 + lane;
      obase[f] = buf[f];                // fully coalesced 256B stores
    }
  }
}

extern "C" void kernel_launch(void* const* d_in, const int* in_sizes, int n_in,
                              void* d_out, int out_size, void* d_ws, size_t ws_size,
                              hipStream_t stream) {
  const float2* means2  = (const float2*)d_in[0];   // (N,2,1)
  const float4* covs4   = (const float4*)d_in[1];   // (N,2,2)
  const float4* colors4 = (const float4*)d_in[2];   // (N,4)
  float* out = (float*)d_out;                       // (768,768,3) fp32

  // 768 blocks = one per row; 4 waves = 4x 192-px segments; 3 blocks/CU:
  // all blocks co-resident, single uniform round, no residency tail.
  render_kernel<<<dim3(H_DIM), dim3(256), 0, stream>>>(
      means2, covs4, colors4, out);
}